// Round 11
// baseline (325.962 us; speedup 1.0000x reference)
//
#include <hip/hip_runtime.h>

// GAT 3-layer, N=100000 nodes, E=1.6M edges (+N self loops), Fin=64, H=128.
// 8-dispatch pipeline:
//   memset cur -> K1{edge partition (per-wave LDS hists, 4096 edges/blk) || gemm0 || zero g}
//   -> p2{cursor scan + deg + rowptr + place} -> agg0 -> gemm1 -> agg1 -> gemm2
//   -> agg2{readout, 2048-way replicated atomic slots} -> finalize.

#define NN 100000
#define NE 1600000
#define ET (NE + NN)   // edges + self loops
#define HD 128
#define NCB 98         // coarse buckets = ceil(NN / 1024)
#define CAP 18432      // bucket capacity (mean 16327, +16 sigma)
#define EB2 391        // edge-partition blocks = ceil(NE / 4096)
#define GB 782         // gemm blocks = ceil(NN / 128)
#define ZB 16          // g-zeroing blocks
#define NSLOT 2048     // replicated readout accumulator slots (~98 atomics/line)

typedef unsigned int uint;
typedef unsigned short ushort;
typedef unsigned char uchar;
typedef __attribute__((ext_vector_type(8))) short bf16x8;
typedef __attribute__((ext_vector_type(8))) ushort u16x8;
typedef __attribute__((ext_vector_type(4))) float f32x4;
typedef __attribute__((ext_vector_type(2))) float f32x2;

__device__ __forceinline__ ushort f2b(float f) {   // fp32 -> bf16 RTN-even
    uint u = __float_as_uint(f);
    return (ushort)((u + 0x7fffu + ((u >> 16) & 1u)) >> 16);
}
__device__ __forceinline__ uchar f2fp8(float f) {  // fp32 -> fp8 e4m3 (OCP), RNE+sat
    return (uchar)(__builtin_amdgcn_cvt_pk_fp8_f32(f, f, 0, false) & 0xff);
}

// ---------------- MFMA GEMM body: Hf8 = fp8(X @ W), fused fp32 alpha epilogue ----------------

template <int K, bool XF32>
__device__ __forceinline__ void gemm_body(int bid, const void* Xp,
                                          const float* __restrict__ W,
                                          const float* __restrict__ a_src,
                                          const float* __restrict__ a_dst,
                                          uchar* __restrict__ Hf8,
                                          float* __restrict__ As,
                                          float* __restrict__ Ad) {
    __shared__ ushort wlds[K * 128];
    const int t = threadIdx.x;

    // stage W -> LDS bf16, swizzled: byte = ((row*K + k)*2) ^ ((row&7)<<4)
    for (int elem = t * 4; elem < K * 128; elem += 1024) {
        float4 wv = *(const float4*)&W[elem];
        int k = elem >> 7, n0 = elem & 127;
        float ws[4] = {wv.x, wv.y, wv.z, wv.w};
        #pragma unroll
        for (int j = 0; j < 4; ++j) {
            int row = n0 + j;
            int byte = ((row * K + k) * 2) ^ ((row & 7) << 4);
            *(ushort*)((char*)wlds + byte) = f2b(ws[j]);
        }
    }
    __syncthreads();

    const int w = t >> 6;
    const int l = t & 63;
    const int c16 = l & 15;
    const int kg = l >> 4;
    const int rowBase = bid * 128 + w * 32;

    f32x4 acc[2][8] = {};

    const int r0c = min(rowBase + c16, NN - 1);
    const int r1c = min(rowBase + 16 + c16, NN - 1);

    #pragma unroll
    for (int ks = 0; ks < K / 32; ++ks) {
        const int k0 = ks * 32 + kg * 8;
        bf16x8 a0, a1;
        if (XF32) {
            const float* Xf = (const float*)Xp;
            float4 lo0 = *(const float4*)&Xf[(size_t)r0c * K + k0];
            float4 hi0 = *(const float4*)&Xf[(size_t)r0c * K + k0 + 4];
            float4 lo1 = *(const float4*)&Xf[(size_t)r1c * K + k0];
            float4 hi1 = *(const float4*)&Xf[(size_t)r1c * K + k0 + 4];
            a0[0] = (short)f2b(lo0.x); a0[1] = (short)f2b(lo0.y);
            a0[2] = (short)f2b(lo0.z); a0[3] = (short)f2b(lo0.w);
            a0[4] = (short)f2b(hi0.x); a0[5] = (short)f2b(hi0.y);
            a0[6] = (short)f2b(hi0.z); a0[7] = (short)f2b(hi0.w);
            a1[0] = (short)f2b(lo1.x); a1[1] = (short)f2b(lo1.y);
            a1[2] = (short)f2b(lo1.z); a1[3] = (short)f2b(lo1.w);
            a1[4] = (short)f2b(hi1.x); a1[5] = (short)f2b(hi1.y);
            a1[6] = (short)f2b(hi1.z); a1[7] = (short)f2b(hi1.w);
        } else {
            const ushort* Xb = (const ushort*)Xp;
            a0 = *(const bf16x8*)(Xb + (size_t)r0c * K + k0);
            a1 = *(const bf16x8*)(Xb + (size_t)r1c * K + k0);
        }
        #pragma unroll
        for (int n = 0; n < 8; ++n) {
            int row = n * 16 + c16;
            int byte = ((row * K + k0) * 2) ^ ((row & 7) << 4);
            bf16x8 b = *(const bf16x8*)((const char*)wlds + byte);
            acc[0][n] = __builtin_amdgcn_mfma_f32_16x16x32_bf16(a0, b, acc[0][n], 0, 0, 0);
            acc[1][n] = __builtin_amdgcn_mfma_f32_16x16x32_bf16(a1, b, acc[1][n], 0, 0, 0);
        }
    }

    float avs[8], avd[8];
    #pragma unroll
    for (int n = 0; n < 8; ++n) {
        avs[n] = a_src[n * 16 + c16];
        avd[n] = a_dst[n * 16 + c16];
    }

    #pragma unroll
    for (int m = 0; m < 2; ++m) {
        #pragma unroll
        for (int j = 0; j < 4; ++j) {
            const int gr = rowBase + m * 16 + kg * 4 + j;
            const bool ok = (gr < NN);
            if (ok) {
                #pragma unroll
                for (int n = 0; n < 8; ++n)
                    Hf8[(size_t)gr * HD + n * 16 + c16] = f2fp8(acc[m][n][j]);
            }
            float ps = 0.f, pd = 0.f;
            #pragma unroll
            for (int n = 0; n < 8; ++n) {
                ps = fmaf(acc[m][n][j], avs[n], ps);
                pd = fmaf(acc[m][n][j], avd[n], pd);
            }
            #pragma unroll
            for (int off = 8; off >= 1; off >>= 1) {
                ps += __shfl_xor(ps, off);
                pd += __shfl_xor(pd, off);
            }
            if (ok && c16 == 0) { As[gr] = ps; Ad[gr] = pd; }
        }
    }
}

// ---------------- K1: edge partition || gemm0 || zero g ----------------
// Partition: 4096 edges/block, per-wave replicated LDS histograms (conflicts
// become intra-wave only), single global reserve atomic per block-bucket.

__global__ __launch_bounds__(256) void k1_kernel(
        const int* __restrict__ ei, int* __restrict__ cur, uint* __restrict__ stage,
        const float* __restrict__ x, const float* __restrict__ W0,
        const float* __restrict__ as0, const float* __restrict__ ad0,
        uchar* __restrict__ hf8, float* __restrict__ As, float* __restrict__ Ad,
        float* __restrict__ g) {
    const int vb = blockIdx.x;
    if (vb < EB2) {
        __shared__ int cnt[4][NCB];
        __shared__ int wbase[4][NCB];
        const int t = threadIdx.x;
        const int w = t >> 6;
        for (int i = t; i < 4 * NCB; i += 256) ((int*)cnt)[i] = 0;
        __syncthreads();
        const int base = vb * 4096;
        int src[16], dst[16];
        #pragma unroll
        for (int i = 0; i < 16; ++i) {
            int e = base + t + i * 256;
            if (e < NE) {
                src[i] = ei[e];
                dst[i] = ei[NE + e];
                atomicAdd(&cnt[w][dst[i] >> 10], 1);
            } else dst[i] = -1;
        }
        __syncthreads();
        if (t < NCB) {
            int c0 = cnt[0][t], c1 = cnt[1][t], c2 = cnt[2][t], c3 = cnt[3][t];
            int tot = c0 + c1 + c2 + c3;
            if (tot) {
                int gb = t * CAP + atomicAdd(&cur[t << 4], tot);  // reserve run
                wbase[0][t] = gb;
                wbase[1][t] = gb + c0;
                wbase[2][t] = gb + c0 + c1;
                wbase[3][t] = gb + c0 + c1 + c2;
            }
        }
        __syncthreads();
        if (t < NCB) {            // per-wave cursors (reuse cnt)
            cnt[0][t] = wbase[0][t];
            cnt[1][t] = wbase[1][t];
            cnt[2][t] = wbase[2][t];
            cnt[3][t] = wbase[3][t];
        }
        __syncthreads();
        #pragma unroll
        for (int i = 0; i < 16; ++i) {
            if (dst[i] >= 0) {
                int pos = atomicAdd(&cnt[w][dst[i] >> 10], 1);
                stage[pos] = ((uint)src[i] << 10) | ((uint)dst[i] & 1023u);
            }
        }
    } else if (vb < EB2 + GB) {
        gemm_body<64, true>(vb - EB2, x, W0, as0, ad0, hf8, As, Ad);
    } else {
        const int zb = vb - (EB2 + GB);
        float4* g4 = (float4*)g;
        for (int i = zb * 4096 + threadIdx.x; i < (zb + 1) * 4096; i += 256)
            g4[i] = (float4){0.f, 0.f, 0.f, 0.f};
    }
}

template <int K>
__global__ __launch_bounds__(256) void gemm_mfma_kernel(const ushort* __restrict__ Xb,
                                                        const float* __restrict__ W,
                                                        const float* __restrict__ a_src,
                                                        const float* __restrict__ a_dst,
                                                        uchar* __restrict__ Hf8,
                                                        float* __restrict__ As,
                                                        float* __restrict__ Ad) {
    gemm_body<K, false>(blockIdx.x, Xb, W, a_src, a_dst, Hf8, As, Ad);
}

// ---------------- p2: cursor scan + per-bucket deg + rowptr + placement ----------------

__global__ __launch_bounds__(256) void p2_fused_kernel(const uint* __restrict__ stage,
                                                       const int* __restrict__ cur,
                                                       int* __restrict__ rowptr,
                                                       int* __restrict__ col) {
    __shared__ int pre[128];
    __shared__ int d[1024];
    __shared__ int ts[256];
    const int t = threadIdx.x, b = blockIdx.x;

    // scan the 98 bucket counts (inclusive) -> exclusive base for this bucket
    int myv = 0;
    if (t < 128) {
        myv = (t < NCB) ? cur[t << 4] : 0;
        pre[t] = myv;
    }
    __syncthreads();
    #pragma unroll
    for (int o = 1; o < 128; o <<= 1) {
        int add = (t < 128 && t >= o) ? pre[t - o] : 0;
        __syncthreads();
        if (t < 128) pre[t] += add;
        __syncthreads();
    }
    const int count = cur[b << 4];
    const int s0 = b * CAP, s1 = s0 + count;
    const int bucketStart = (pre[b] - count) + (b << 10);  // excl edge prefix + self loops
    __syncthreads();

    #pragma unroll
    for (int i = t; i < 1024; i += 256) d[i] = 0;
    __syncthreads();
    for (int i = s0 + t; i < s1; i += 256) atomicAdd(&d[stage[i] & 1023u], 1);
    __syncthreads();

    int4 a = *(const int4*)&d[t * 4];          // degs of local nodes 4t..4t+3
    int tsum = a.x + a.y + a.z + a.w;
    ts[t] = tsum;
    __syncthreads();
    #pragma unroll
    for (int o = 1; o < 256; o <<= 1) {
        int add = (t >= o) ? ts[t - o] : 0;
        __syncthreads();
        ts[t] += add;
        __syncthreads();
    }
    int q0 = ts[t] - tsum;                     // exclusive deg prefix
    int e0 = bucketStart + q0 + t * 4;         // rowptr of node 4t (+local self loops)
    int e1 = e0 + a.x + 1;
    int e2 = e1 + a.y + 1;
    int e3 = e2 + a.z + 1;
    int node0 = (b << 10) + t * 4;
    if (node0 + 3 < NN) {
        rowptr[node0]     = e0;
        rowptr[node0 + 1] = e1;
        rowptr[node0 + 2] = e2;
        rowptr[node0 + 3] = e3;
        col[e0 + a.x] = node0;                 // self loop -> last slot
        col[e1 + a.y] = node0 + 1;
        col[e2 + a.z] = node0 + 2;
        col[e3 + a.w] = node0 + 3;
    } else {
        int ee[4] = {e0, e1, e2, e3};
        int aa[4] = {a.x, a.y, a.z, a.w};
        #pragma unroll
        for (int j = 0; j < 4; ++j)
            if (node0 + j < NN) {
                rowptr[node0 + j] = ee[j];
                col[ee[j] + aa[j]] = node0 + j;
            }
    }
    if (b == NCB - 1 && t == 0) rowptr[NN] = ET;
    *(int4*)&d[t * 4] = (int4){e0, e1, e2, e3};   // becomes the placement cursor
    __syncthreads();
    for (int i = s0 + t; i < s1; i += 256) {
        uint v = stage[i];
        int pos = atomicAdd(&d[v & 1023u], 1);
        col[pos] = (int)(v >> 10);
    }
}

// ---------------- per-dst online softmax + aggregate (standalone, bf16 out) ----------------

__global__ __launch_bounds__(256) void aggregate_kernel(const uchar* __restrict__ h8,
                                                        const float* __restrict__ As,
                                                        const float* __restrict__ Ad,
                                                        const int* __restrict__ rowptr,
                                                        const int* __restrict__ col,
                                                        const float* __restrict__ bias,
                                                        ushort* __restrict__ out,
                                                        int relu) {
    const int lane  = threadIdx.x & 63;
    const int sub   = lane & 31;        // lane within node
    const int g2    = sub >> 4;         // edge-group 0/1
    const int q     = sub & 15;         // feature lane -> feats [q*8, q*8+8)
    const int lbase = lane & 32;        // node-half base for shfl
    const int node  = blockIdx.x * 8 + ((threadIdx.x >> 6) << 1) + (lane >> 5);
    // grid is exact: 12500 * 8 == NN

    const int start = rowptr[node];
    const int end   = rowptr[node + 1];
    const float ad_i = Ad[node];

    float m = -1e30f;
    float denom = 0.f;
    f32x2 acc2[4] = {};

    for (int base = start; base < end; base += 32) {
        const int cnt = min(32, end - base);
        int   sc = 0;
        float e  = -1e30f;
        if (sub < cnt) {
            sc = col[base + sub];
            float a = As[sc] + ad_i;
            e = (a > 0.f) ? a : 0.2f * a;       // leaky_relu 0.2
        }
        float cmax = e;
        #pragma unroll
        for (int off = 16; off >= 1; off >>= 1) cmax = fmaxf(cmax, __shfl_xor(cmax, off));
        float s = __expf(fminf(m - cmax, 0.f));  // branchless online rescale
        m = fmaxf(m, cmax);
        f32x2 s2 = {s, s};
        #pragma unroll
        for (int i = 0; i < 4; ++i) acc2[i] *= s2;
        denom *= s;

        float w = (sub < cnt) ? __expf(e - m) : 0.f;
        denom += w;

        for (int jj = 0; jj < cnt; jj += 8) {
            const int i0 = lbase | (jj + 4 * g2);
            float wv[4]; int sv[4];
            #pragma unroll
            for (int u = 0; u < 4; ++u) {
                wv[u] = __shfl(w, i0 + u);
                sv[u] = __shfl(sc, i0 + u);
            }
            uint2 vv[4];
            #pragma unroll
            for (int u = 0; u < 4; ++u)
                vv[u] = *(const uint2*)(h8 + (size_t)sv[u] * HD + q * 8);
            #pragma unroll
            for (int u = 0; u < 4; ++u) {
                f32x2 w2 = {wv[u], wv[u]};
                f32x2 p0 = __builtin_amdgcn_cvt_pk_f32_fp8(vv[u].x, false);
                f32x2 p1 = __builtin_amdgcn_cvt_pk_f32_fp8(vv[u].x, true);
                f32x2 p2 = __builtin_amdgcn_cvt_pk_f32_fp8(vv[u].y, false);
                f32x2 p3 = __builtin_amdgcn_cvt_pk_f32_fp8(vv[u].y, true);
                acc2[0] = __builtin_elementwise_fma(w2, p0, acc2[0]);
                acc2[1] = __builtin_elementwise_fma(w2, p1, acc2[1]);
                acc2[2] = __builtin_elementwise_fma(w2, p2, acc2[2]);
                acc2[3] = __builtin_elementwise_fma(w2, p3, acc2[3]);
            }
        }
    }

    float accf[8];
    #pragma unroll
    for (int i = 0; i < 4; ++i) { accf[2 * i] = acc2[i][0]; accf[2 * i + 1] = acc2[i][1]; }

    // cross-group feature reduce (xor 16 combines the node's two groups)
    #pragma unroll
    for (int i = 0; i < 8; ++i) accf[i] += __shfl_xor(accf[i], 16);
    #pragma unroll
    for (int off = 16; off >= 1; off >>= 1) denom += __shfl_xor(denom, off);

    if (g2 == 0) {
        float inv = 1.0f / denom;
        float4 bv0 = *(const float4*)&bias[q * 8];
        float4 bv1 = *(const float4*)&bias[q * 8 + 4];
        float bb[8] = {bv0.x, bv0.y, bv0.z, bv0.w, bv1.x, bv1.y, bv1.z, bv1.w};
        u16x8 o;
        #pragma unroll
        for (int i = 0; i < 8; ++i) {
            float v = fmaf(accf[i], inv, bb[i]);
            if (relu) v = fmaxf(v, 0.f);
            o[i] = f2b(v);
        }
        *(u16x8*)&out[(size_t)node * HD + q * 8] = o;
    }
}

// ---------------- layer-2 aggregate + graph-sum readout ----------------

__global__ __launch_bounds__(256) void aggregate_readout_kernel(
        const uchar* __restrict__ h8, const float* __restrict__ As,
        const float* __restrict__ Ad, const int* __restrict__ rowptr,
        const int* __restrict__ col, float* __restrict__ g) {
    __shared__ float gsum[128];
    const int tt    = threadIdx.x;
    const int lane  = tt & 63;
    const int sub   = lane & 31;
    const int g2    = sub >> 4;
    const int q     = sub & 15;
    const int lbase = lane & 32;
    const int node  = blockIdx.x * 8 + ((tt >> 6) << 1) + (lane >> 5);

    if (tt < 128) gsum[tt] = 0.f;
    __syncthreads();

    const int start = rowptr[node];
    const int end   = rowptr[node + 1];
    const float ad_i = Ad[node];

    float m = -1e30f;
    float denom = 0.f;
    f32x2 acc2[4] = {};

    for (int base = start; base < end; base += 32) {
        const int cnt = min(32, end - base);
        int   sc = 0;
        float e  = -1e30f;
        if (sub < cnt) {
            sc = col[base + sub];
            float a = As[sc] + ad_i;
            e = (a > 0.f) ? a : 0.2f * a;
        }
        float cmax = e;
        #pragma unroll
        for (int off = 16; off >= 1; off >>= 1) cmax = fmaxf(cmax, __shfl_xor(cmax, off));
        float s = __expf(fminf(m - cmax, 0.f));
        m = fmaxf(m, cmax);
        f32x2 s2 = {s, s};
        #pragma unroll
        for (int i = 0; i < 4; ++i) acc2[i] *= s2;
        denom *= s;

        float w = (sub < cnt) ? __expf(e - m) : 0.f;
        denom += w;

        for (int jj = 0; jj < cnt; jj += 8) {
            const int i0 = lbase | (jj + 4 * g2);
            float wv[4]; int sv[4];
            #pragma unroll
            for (int u = 0; u < 4; ++u) {
                wv[u] = __shfl(w, i0 + u);
                sv[u] = __shfl(sc, i0 + u);
            }
            uint2 vv[4];
            #pragma unroll
            for (int u = 0; u < 4; ++u)
                vv[u] = *(const uint2*)(h8 + (size_t)sv[u] * HD + q * 8);
            #pragma unroll
            for (int u = 0; u < 4; ++u) {
                f32x2 w2 = {wv[u], wv[u]};
                f32x2 p0 = __builtin_amdgcn_cvt_pk_f32_fp8(vv[u].x, false);
                f32x2 p1 = __builtin_amdgcn_cvt_pk_f32_fp8(vv[u].x, true);
                f32x2 p2 = __builtin_amdgcn_cvt_pk_f32_fp8(vv[u].y, false);
                f32x2 p3 = __builtin_amdgcn_cvt_pk_f32_fp8(vv[u].y, true);
                acc2[0] = __builtin_elementwise_fma(w2, p0, acc2[0]);
                acc2[1] = __builtin_elementwise_fma(w2, p1, acc2[1]);
                acc2[2] = __builtin_elementwise_fma(w2, p2, acc2[2]);
                acc2[3] = __builtin_elementwise_fma(w2, p3, acc2[3]);
            }
        }
    }

    float accf[8];
    #pragma unroll
    for (int i = 0; i < 4; ++i) { accf[2 * i] = acc2[i][0]; accf[2 * i + 1] = acc2[i][1]; }
    #pragma unroll
    for (int i = 0; i < 8; ++i) accf[i] += __shfl_xor(accf[i], 16);
    #pragma unroll
    for (int off = 16; off >= 1; off >>= 1) denom += __shfl_xor(denom, off);

    float inv = 1.0f / denom;
    if (g2 == 0) {
        #pragma unroll
        for (int i = 0; i < 8; ++i) atomicAdd(&gsum[q * 8 + i], accf[i] * inv);
    }
    __syncthreads();
    if (tt < 128)
        atomicAdd(&g[(blockIdx.x & (NSLOT - 1)) * 128 + tt], gsum[tt]);
}

// ---------------- finalize: out = (sum_slots(g)/NN + b2) @ Wp + bp ----------------

__global__ void finalize_kernel(const float* __restrict__ g, const float* __restrict__ b2,
                                const float* __restrict__ Wp, const float* __restrict__ bp,
                                float* __restrict__ out) {
    __shared__ float half2sum[128];
    __shared__ float red[2];
    const int t = threadIdx.x;          // 256 threads: t&127 = feature, t>>7 = half
    const int f = t & 127;
    const int h = t >> 7;
    float s0 = 0.f, s1 = 0.f, s2 = 0.f, s3 = 0.f;
    for (int r = h * (NSLOT / 2); r < (h + 1) * (NSLOT / 2); r += 4) {
        s0 += g[(r + 0) * 128 + f];
        s1 += g[(r + 1) * 128 + f];
        s2 += g[(r + 2) * 128 + f];
        s3 += g[(r + 3) * 128 + f];
    }
    float s = (s0 + s1) + (s2 + s3);
    if (h == 1) half2sum[f] = s;
    __syncthreads();
    if (h == 0) {
        s += half2sum[f];
        float v = (s * (1.0f / NN) + b2[f]) * Wp[f];
        #pragma unroll
        for (int m = 32; m >= 1; m >>= 1) v += __shfl_xor(v, m);
        if ((f & 63) == 0) red[f >> 6] = v;
    }
    __syncthreads();
    if (t == 0) out[0] = red[0] + red[1] + bp[0];
}

// ---------------- launch ----------------

extern "C" void kernel_launch(void* const* d_in, const int* in_sizes, int n_in,
                              void* d_out, int out_size, void* d_ws, size_t ws_size,
                              hipStream_t stream) {
    const float* x   = (const float*)d_in[0];
    const int*   ei  = (const int*)d_in[1];
    const float* W0  = (const float*)d_in[2];
    const float* W1  = (const float*)d_in[3];
    const float* W2  = (const float*)d_in[4];
    const float* as0 = (const float*)d_in[5];
    const float* as1 = (const float*)d_in[6];
    const float* as2 = (const float*)d_in[7];
    const float* ad0 = (const float*)d_in[8];
    const float* ad1 = (const float*)d_in[9];
    const float* ad2 = (const float*)d_in[10];
    const float* b0  = (const float*)d_in[11];
    const float* b1  = (const float*)d_in[12];
    const float* b2  = (const float*)d_in[13];
    const float* Wp  = (const float*)d_in[14];
    const float* bp  = (const float*)d_in[15];
    float* out = (float*)d_out;

    char* p = (char*)d_ws;
    auto alloc = [&](size_t bytes) {
        char* r = p;
        p += (bytes + 255) & ~(size_t)255;
        return r;
    };
    uchar*  hf8    = (uchar*)alloc((size_t)NN * HD);        // fp8 gather rows
    ushort* abf    = (ushort*)alloc((size_t)NN * HD * 2);   // layer-0/1 aggregate output
    float* As      = (float*)alloc((size_t)NN * 4);
    float* Ad      = (float*)alloc((size_t)NN * 4);
    int*   rowptr  = (int*)alloc((size_t)(NN + 1) * 4);
    uint*  stage   = (uint*)alloc((size_t)NCB * CAP * 4);   // fixed-cap buckets
    int*   col     = (int*)alloc((size_t)ET * 4);
    int*   cur     = (int*)alloc((size_t)NCB * 16 * 4);     // padded cursors
    float* g       = (float*)alloc((size_t)NSLOT * 128 * 4);

    hipMemsetAsync(cur, 0, (size_t)NCB * 16 * 4, stream);

    // K1: edge partition || layer-0 gemm (x fp32 in-reg convert, W0 via LDS) || zero g
    k1_kernel<<<EB2 + GB + ZB, 256, 0, stream>>>(ei, cur, stage, x, W0, as0, ad0,
                                                 hf8, As, Ad, g);
    // p2: cursor scan + deg + rowptr + self loops + placement
    p2_fused_kernel<<<NCB, 256, 0, stream>>>(stage, cur, rowptr, col);

    const int AB = NN / 8;  // 12500 (exact)

    // layer 0 aggregate
    aggregate_kernel<<<AB, 256, 0, stream>>>(hf8, As, Ad, rowptr, col, b0, abf, 1);
    // layer 1
    gemm_mfma_kernel<128><<<GB, 256, 0, stream>>>(abf, W1, as1, ad1, hf8, As, Ad);
    aggregate_kernel<<<AB, 256, 0, stream>>>(hf8, As, Ad, rowptr, col, b1, abf, 1);
    // layer 2 (aggregate fused with graph-sum readout; bias b2 folded into finalize)
    gemm_mfma_kernel<128><<<GB, 256, 0, stream>>>(abf, W2, as2, ad2, hf8, As, Ad);
    aggregate_readout_kernel<<<AB, 256, 0, stream>>>(hf8, As, Ad, rowptr, col, g);

    finalize_kernel<<<1, 256, 0, stream>>>(g, b2, Wp, bp, out);
}

// Round 12
// 294.620 us; speedup vs baseline: 1.1064x; 1.1064x over previous
//
#include <hip/hip_runtime.h>

// GAT 3-layer, N=100000 nodes, E=1.6M edges (+N self loops), Fin=64, H=128.
// 9-dispatch pipeline:
//   memset cur -> K1{edge partition || gemm0 || zero g} -> p2{CSR build}
//   -> agg0 -> gemm1 -> agg1 -> gemm2 -> agg2 (plain, bias=b2) -> sum -> finalize.
// NOTE: readout deliberately NOT fused into agg2 — the block-wide gsum reduction
// structure (2x syncthreads + LDS atomics) measured +50us over the plain kernel
// (r8-r11), while the unfused sum_kernel costs ~12us.

#define NN 100000
#define NE 1600000
#define ET (NE + NN)   // edges + self loops
#define HD 128
#define NCB 98         // coarse buckets = ceil(NN / 1024)
#define CAP 18432      // bucket capacity (mean 16327, +16 sigma)
#define EB2 391        // edge-partition blocks = ceil(NE / 4096)
#define GB 782         // gemm blocks = ceil(NN / 128)

typedef unsigned int uint;
typedef unsigned short ushort;
typedef unsigned char uchar;
typedef __attribute__((ext_vector_type(8))) short bf16x8;
typedef __attribute__((ext_vector_type(8))) ushort u16x8;
typedef __attribute__((ext_vector_type(4))) float f32x4;
typedef __attribute__((ext_vector_type(2))) float f32x2;

__device__ __forceinline__ ushort f2b(float f) {   // fp32 -> bf16 RTN-even
    uint u = __float_as_uint(f);
    return (ushort)((u + 0x7fffu + ((u >> 16) & 1u)) >> 16);
}
__device__ __forceinline__ float b2f_lo(uint v) { return __uint_as_float(v << 16); }
__device__ __forceinline__ float b2f_hi(uint v) { return __uint_as_float(v & 0xffff0000u); }
__device__ __forceinline__ uchar f2fp8(float f) {  // fp32 -> fp8 e4m3 (OCP), RNE+sat
    return (uchar)(__builtin_amdgcn_cvt_pk_fp8_f32(f, f, 0, false) & 0xff);
}

// ---------------- MFMA GEMM body: Hf8 = fp8(X @ W), fused fp32 alpha epilogue ----------------

template <int K, bool XF32>
__device__ __forceinline__ void gemm_body(int bid, const void* Xp,
                                          const float* __restrict__ W,
                                          const float* __restrict__ a_src,
                                          const float* __restrict__ a_dst,
                                          uchar* __restrict__ Hf8,
                                          float* __restrict__ As,
                                          float* __restrict__ Ad) {
    __shared__ ushort wlds[K * 128];
    const int t = threadIdx.x;

    // stage W -> LDS bf16, swizzled: byte = ((row*K + k)*2) ^ ((row&7)<<4)
    for (int elem = t * 4; elem < K * 128; elem += 1024) {
        float4 wv = *(const float4*)&W[elem];
        int k = elem >> 7, n0 = elem & 127;
        float ws[4] = {wv.x, wv.y, wv.z, wv.w};
        #pragma unroll
        for (int j = 0; j < 4; ++j) {
            int row = n0 + j;
            int byte = ((row * K + k) * 2) ^ ((row & 7) << 4);
            *(ushort*)((char*)wlds + byte) = f2b(ws[j]);
        }
    }
    __syncthreads();

    const int w = t >> 6;
    const int l = t & 63;
    const int c16 = l & 15;
    const int kg = l >> 4;
    const int rowBase = bid * 128 + w * 32;

    f32x4 acc[2][8] = {};

    const int r0c = min(rowBase + c16, NN - 1);
    const int r1c = min(rowBase + 16 + c16, NN - 1);

    #pragma unroll
    for (int ks = 0; ks < K / 32; ++ks) {
        const int k0 = ks * 32 + kg * 8;
        bf16x8 a0, a1;
        if (XF32) {
            const float* Xf = (const float*)Xp;
            float4 lo0 = *(const float4*)&Xf[(size_t)r0c * K + k0];
            float4 hi0 = *(const float4*)&Xf[(size_t)r0c * K + k0 + 4];
            float4 lo1 = *(const float4*)&Xf[(size_t)r1c * K + k0];
            float4 hi1 = *(const float4*)&Xf[(size_t)r1c * K + k0 + 4];
            a0[0] = (short)f2b(lo0.x); a0[1] = (short)f2b(lo0.y);
            a0[2] = (short)f2b(lo0.z); a0[3] = (short)f2b(lo0.w);
            a0[4] = (short)f2b(hi0.x); a0[5] = (short)f2b(hi0.y);
            a0[6] = (short)f2b(hi0.z); a0[7] = (short)f2b(hi0.w);
            a1[0] = (short)f2b(lo1.x); a1[1] = (short)f2b(lo1.y);
            a1[2] = (short)f2b(lo1.z); a1[3] = (short)f2b(lo1.w);
            a1[4] = (short)f2b(hi1.x); a1[5] = (short)f2b(hi1.y);
            a1[6] = (short)f2b(hi1.z); a1[7] = (short)f2b(hi1.w);
        } else {
            const ushort* Xb = (const ushort*)Xp;
            a0 = *(const bf16x8*)(Xb + (size_t)r0c * K + k0);
            a1 = *(const bf16x8*)(Xb + (size_t)r1c * K + k0);
        }
        #pragma unroll
        for (int n = 0; n < 8; ++n) {
            int row = n * 16 + c16;
            int byte = ((row * K + k0) * 2) ^ ((row & 7) << 4);
            bf16x8 b = *(const bf16x8*)((const char*)wlds + byte);
            acc[0][n] = __builtin_amdgcn_mfma_f32_16x16x32_bf16(a0, b, acc[0][n], 0, 0, 0);
            acc[1][n] = __builtin_amdgcn_mfma_f32_16x16x32_bf16(a1, b, acc[1][n], 0, 0, 0);
        }
    }

    float avs[8], avd[8];
    #pragma unroll
    for (int n = 0; n < 8; ++n) {
        avs[n] = a_src[n * 16 + c16];
        avd[n] = a_dst[n * 16 + c16];
    }

    #pragma unroll
    for (int m = 0; m < 2; ++m) {
        #pragma unroll
        for (int j = 0; j < 4; ++j) {
            const int gr = rowBase + m * 16 + kg * 4 + j;
            const bool ok = (gr < NN);
            if (ok) {
                #pragma unroll
                for (int n = 0; n < 8; ++n)
                    Hf8[(size_t)gr * HD + n * 16 + c16] = f2fp8(acc[m][n][j]);
            }
            float ps = 0.f, pd = 0.f;
            #pragma unroll
            for (int n = 0; n < 8; ++n) {
                ps = fmaf(acc[m][n][j], avs[n], ps);
                pd = fmaf(acc[m][n][j], avd[n], pd);
            }
            #pragma unroll
            for (int off = 8; off >= 1; off >>= 1) {
                ps += __shfl_xor(ps, off);
                pd += __shfl_xor(pd, off);
            }
            if (ok && c16 == 0) { As[gr] = ps; Ad[gr] = pd; }
        }
    }
}

// ---------------- K1: edge partition || gemm0 || zero g ----------------

__global__ __launch_bounds__(256) void k1_kernel(
        const int* __restrict__ ei, int* __restrict__ cur, uint* __restrict__ stage,
        const float* __restrict__ x, const float* __restrict__ W0,
        const float* __restrict__ as0, const float* __restrict__ ad0,
        uchar* __restrict__ hf8, float* __restrict__ As, float* __restrict__ Ad,
        float* __restrict__ g) {
    const int vb = blockIdx.x;
    if (vb < EB2) {
        __shared__ int cnt[4][NCB];
        __shared__ int wbase[4][NCB];
        const int t = threadIdx.x;
        const int w = t >> 6;
        for (int i = t; i < 4 * NCB; i += 256) ((int*)cnt)[i] = 0;
        __syncthreads();
        const int base = vb * 4096;
        int src[16], dst[16];
        #pragma unroll
        for (int i = 0; i < 16; ++i) {
            int e = base + t + i * 256;
            if (e < NE) {
                src[i] = ei[e];
                dst[i] = ei[NE + e];
                atomicAdd(&cnt[w][dst[i] >> 10], 1);
            } else dst[i] = -1;
        }
        __syncthreads();
        if (t < NCB) {
            int c0 = cnt[0][t], c1 = cnt[1][t], c2 = cnt[2][t], c3 = cnt[3][t];
            int tot = c0 + c1 + c2 + c3;
            if (tot) {
                int gb = t * CAP + atomicAdd(&cur[t << 4], tot);  // reserve run
                wbase[0][t] = gb;
                wbase[1][t] = gb + c0;
                wbase[2][t] = gb + c0 + c1;
                wbase[3][t] = gb + c0 + c1 + c2;
            }
        }
        __syncthreads();
        if (t < NCB) {            // per-wave cursors (reuse cnt)
            cnt[0][t] = wbase[0][t];
            cnt[1][t] = wbase[1][t];
            cnt[2][t] = wbase[2][t];
            cnt[3][t] = wbase[3][t];
        }
        __syncthreads();
        #pragma unroll
        for (int i = 0; i < 16; ++i) {
            if (dst[i] >= 0) {
                int pos = atomicAdd(&cnt[w][dst[i] >> 10], 1);
                stage[pos] = ((uint)src[i] << 10) | ((uint)dst[i] & 1023u);
            }
        }
    } else if (vb < EB2 + GB) {
        gemm_body<64, true>(vb - EB2, x, W0, as0, ad0, hf8, As, Ad);
    } else {
        if (threadIdx.x < 128) g[threadIdx.x] = 0.f;
    }
}

template <int K>
__global__ __launch_bounds__(256) void gemm_mfma_kernel(const ushort* __restrict__ Xb,
                                                        const float* __restrict__ W,
                                                        const float* __restrict__ a_src,
                                                        const float* __restrict__ a_dst,
                                                        uchar* __restrict__ Hf8,
                                                        float* __restrict__ As,
                                                        float* __restrict__ Ad) {
    gemm_body<K, false>(blockIdx.x, Xb, W, a_src, a_dst, Hf8, As, Ad);
}

// ---------------- p2: cursor scan + per-bucket deg + rowptr + placement ----------------

__global__ __launch_bounds__(256) void p2_fused_kernel(const uint* __restrict__ stage,
                                                       const int* __restrict__ cur,
                                                       int* __restrict__ rowptr,
                                                       int* __restrict__ col) {
    __shared__ int pre[128];
    __shared__ int d[1024];
    __shared__ int ts[256];
    const int t = threadIdx.x, b = blockIdx.x;

    // scan the 98 bucket counts (inclusive) -> exclusive base for this bucket
    int myv = 0;
    if (t < 128) {
        myv = (t < NCB) ? cur[t << 4] : 0;
        pre[t] = myv;
    }
    __syncthreads();
    #pragma unroll
    for (int o = 1; o < 128; o <<= 1) {
        int add = (t < 128 && t >= o) ? pre[t - o] : 0;
        __syncthreads();
        if (t < 128) pre[t] += add;
        __syncthreads();
    }
    const int count = cur[b << 4];
    const int s0 = b * CAP, s1 = s0 + count;
    const int bucketStart = (pre[b] - count) + (b << 10);  // excl edge prefix + self loops
    __syncthreads();

    #pragma unroll
    for (int i = t; i < 1024; i += 256) d[i] = 0;
    __syncthreads();
    for (int i = s0 + t; i < s1; i += 256) atomicAdd(&d[stage[i] & 1023u], 1);
    __syncthreads();

    int4 a = *(const int4*)&d[t * 4];          // degs of local nodes 4t..4t+3
    int tsum = a.x + a.y + a.z + a.w;
    ts[t] = tsum;
    __syncthreads();
    #pragma unroll
    for (int o = 1; o < 256; o <<= 1) {
        int add = (t >= o) ? ts[t - o] : 0;
        __syncthreads();
        ts[t] += add;
        __syncthreads();
    }
    int q0 = ts[t] - tsum;                     // exclusive deg prefix
    int e0 = bucketStart + q0 + t * 4;         // rowptr of node 4t (+local self loops)
    int e1 = e0 + a.x + 1;
    int e2 = e1 + a.y + 1;
    int e3 = e2 + a.z + 1;
    int node0 = (b << 10) + t * 4;
    if (node0 + 3 < NN) {
        rowptr[node0]     = e0;
        rowptr[node0 + 1] = e1;
        rowptr[node0 + 2] = e2;
        rowptr[node0 + 3] = e3;
        col[e0 + a.x] = node0;                 // self loop -> last slot
        col[e1 + a.y] = node0 + 1;
        col[e2 + a.z] = node0 + 2;
        col[e3 + a.w] = node0 + 3;
    } else {
        int ee[4] = {e0, e1, e2, e3};
        int aa[4] = {a.x, a.y, a.z, a.w};
        #pragma unroll
        for (int j = 0; j < 4; ++j)
            if (node0 + j < NN) {
                rowptr[node0 + j] = ee[j];
                col[ee[j] + aa[j]] = node0 + j;
            }
    }
    if (b == NCB - 1 && t == 0) rowptr[NN] = ET;
    *(int4*)&d[t * 4] = (int4){e0, e1, e2, e3};   // becomes the placement cursor
    __syncthreads();
    for (int i = s0 + t; i < s1; i += 256) {
        uint v = stage[i];
        int pos = atomicAdd(&d[v & 1023u], 1);
        col[pos] = (int)(v >> 10);
    }
}

// ---------------- per-dst online softmax + aggregate (standalone, bf16 out) ----------------

__global__ __launch_bounds__(256) void aggregate_kernel(const uchar* __restrict__ h8,
                                                        const float* __restrict__ As,
                                                        const float* __restrict__ Ad,
                                                        const int* __restrict__ rowptr,
                                                        const int* __restrict__ col,
                                                        const float* __restrict__ bias,
                                                        ushort* __restrict__ out,
                                                        int relu) {
    const int lane  = threadIdx.x & 63;
    const int sub   = lane & 31;        // lane within node
    const int g2    = sub >> 4;         // edge-group 0/1
    const int q     = sub & 15;         // feature lane -> feats [q*8, q*8+8)
    const int lbase = lane & 32;        // node-half base for shfl
    const int node  = blockIdx.x * 8 + ((threadIdx.x >> 6) << 1) + (lane >> 5);
    // grid is exact: 12500 * 8 == NN

    const int start = rowptr[node];
    const int end   = rowptr[node + 1];
    const float ad_i = Ad[node];

    float m = -1e30f;
    float denom = 0.f;
    f32x2 acc2[4] = {};

    for (int base = start; base < end; base += 32) {
        const int cnt = min(32, end - base);
        int   sc = 0;
        float e  = -1e30f;
        if (sub < cnt) {
            sc = col[base + sub];
            float a = As[sc] + ad_i;
            e = (a > 0.f) ? a : 0.2f * a;       // leaky_relu 0.2
        }
        float cmax = e;
        #pragma unroll
        for (int off = 16; off >= 1; off >>= 1) cmax = fmaxf(cmax, __shfl_xor(cmax, off));
        float s = __expf(fminf(m - cmax, 0.f));  // branchless online rescale
        m = fmaxf(m, cmax);
        f32x2 s2 = {s, s};
        #pragma unroll
        for (int i = 0; i < 4; ++i) acc2[i] *= s2;
        denom *= s;

        float w = (sub < cnt) ? __expf(e - m) : 0.f;
        denom += w;

        for (int jj = 0; jj < cnt; jj += 8) {
            const int i0 = lbase | (jj + 4 * g2);
            float wv[4]; int sv[4];
            #pragma unroll
            for (int u = 0; u < 4; ++u) {
                wv[u] = __shfl(w, i0 + u);
                sv[u] = __shfl(sc, i0 + u);
            }
            uint2 vv[4];
            #pragma unroll
            for (int u = 0; u < 4; ++u)
                vv[u] = *(const uint2*)(h8 + (size_t)sv[u] * HD + q * 8);
            #pragma unroll
            for (int u = 0; u < 4; ++u) {
                f32x2 w2 = {wv[u], wv[u]};
                f32x2 p0 = __builtin_amdgcn_cvt_pk_f32_fp8(vv[u].x, false);
                f32x2 p1 = __builtin_amdgcn_cvt_pk_f32_fp8(vv[u].x, true);
                f32x2 p2 = __builtin_amdgcn_cvt_pk_f32_fp8(vv[u].y, false);
                f32x2 p3 = __builtin_amdgcn_cvt_pk_f32_fp8(vv[u].y, true);
                acc2[0] = __builtin_elementwise_fma(w2, p0, acc2[0]);
                acc2[1] = __builtin_elementwise_fma(w2, p1, acc2[1]);
                acc2[2] = __builtin_elementwise_fma(w2, p2, acc2[2]);
                acc2[3] = __builtin_elementwise_fma(w2, p3, acc2[3]);
            }
        }
    }

    float accf[8];
    #pragma unroll
    for (int i = 0; i < 4; ++i) { accf[2 * i] = acc2[i][0]; accf[2 * i + 1] = acc2[i][1]; }

    // cross-group feature reduce (xor 16 combines the node's two groups)
    #pragma unroll
    for (int i = 0; i < 8; ++i) accf[i] += __shfl_xor(accf[i], 16);
    #pragma unroll
    for (int off = 16; off >= 1; off >>= 1) denom += __shfl_xor(denom, off);

    if (g2 == 0) {
        float inv = 1.0f / denom;
        float4 bv0 = *(const float4*)&bias[q * 8];
        float4 bv1 = *(const float4*)&bias[q * 8 + 4];
        float bb[8] = {bv0.x, bv0.y, bv0.z, bv0.w, bv1.x, bv1.y, bv1.z, bv1.w};
        u16x8 o;
        #pragma unroll
        for (int i = 0; i < 8; ++i) {
            float v = fmaf(accf[i], inv, bb[i]);
            if (relu) v = fmaxf(v, 0.f);
            o[i] = f2b(v);
        }
        *(u16x8*)&out[(size_t)node * HD + q * 8] = o;
    }
}

// ---------------- readout: graph sum of bf16 h -> g[128] ----------------

__global__ __launch_bounds__(256) void sum_kernel(const ushort* __restrict__ h,
                                                  float* __restrict__ g) {
    int t = threadIdx.x;
    int wave = t >> 6, lane = t & 63;
    float sx = 0.f, sy = 0.f;
    for (int r = blockIdx.x * 4 + wave; r < NN; r += gridDim.x * 4) {
        uint v = *(const uint*)&h[(size_t)r * HD + lane * 2];
        sx += b2f_lo(v); sy += b2f_hi(v);
    }
    __shared__ float sm[512];
    sm[wave * 128 + lane * 2]     = sx;
    sm[wave * 128 + lane * 2 + 1] = sy;
    __syncthreads();
    if (t < 128) {
        float s = sm[t] + sm[128 + t] + sm[256 + t] + sm[384 + t];
        atomicAdd(&g[t], s);
    }
}

__global__ void finalize_kernel(const float* __restrict__ g, const float* __restrict__ Wp,
                                const float* __restrict__ bp, float* __restrict__ out) {
    int t = threadIdx.x;
    float v = g[t] * (1.0f / NN) * Wp[t];
    #pragma unroll
    for (int m = 32; m >= 1; m >>= 1) v += __shfl_xor(v, m);
    __shared__ float red[2];
    if ((t & 63) == 0) red[t >> 6] = v;
    __syncthreads();
    if (t == 0) out[0] = red[0] + red[1] + bp[0];
}

// ---------------- launch ----------------

extern "C" void kernel_launch(void* const* d_in, const int* in_sizes, int n_in,
                              void* d_out, int out_size, void* d_ws, size_t ws_size,
                              hipStream_t stream) {
    const float* x   = (const float*)d_in[0];
    const int*   ei  = (const int*)d_in[1];
    const float* W0  = (const float*)d_in[2];
    const float* W1  = (const float*)d_in[3];
    const float* W2  = (const float*)d_in[4];
    const float* as0 = (const float*)d_in[5];
    const float* as1 = (const float*)d_in[6];
    const float* as2 = (const float*)d_in[7];
    const float* ad0 = (const float*)d_in[8];
    const float* ad1 = (const float*)d_in[9];
    const float* ad2 = (const float*)d_in[10];
    const float* b0  = (const float*)d_in[11];
    const float* b1  = (const float*)d_in[12];
    const float* b2  = (const float*)d_in[13];
    const float* Wp  = (const float*)d_in[14];
    const float* bp  = (const float*)d_in[15];
    float* out = (float*)d_out;

    char* p = (char*)d_ws;
    auto alloc = [&](size_t bytes) {
        char* r = p;
        p += (bytes + 255) & ~(size_t)255;
        return r;
    };
    uchar*  hf8    = (uchar*)alloc((size_t)NN * HD);        // fp8 gather rows
    ushort* abf    = (ushort*)alloc((size_t)NN * HD * 2);   // aggregate output (bf16)
    float* As      = (float*)alloc((size_t)NN * 4);
    float* Ad      = (float*)alloc((size_t)NN * 4);
    int*   rowptr  = (int*)alloc((size_t)(NN + 1) * 4);
    uint*  stage   = (uint*)alloc((size_t)NCB * CAP * 4);   // fixed-cap buckets
    int*   col     = (int*)alloc((size_t)ET * 4);
    int*   cur     = (int*)alloc((size_t)NCB * 16 * 4);     // padded cursors
    float* g       = (float*)alloc(512);

    hipMemsetAsync(cur, 0, (size_t)NCB * 16 * 4, stream);

    // K1: edge partition || layer-0 gemm (x fp32 in-reg convert, W0 via LDS) || zero g
    k1_kernel<<<EB2 + GB + 1, 256, 0, stream>>>(ei, cur, stage, x, W0, as0, ad0,
                                                hf8, As, Ad, g);
    // p2: cursor scan + deg + rowptr + self loops + placement
    p2_fused_kernel<<<NCB, 256, 0, stream>>>(stage, cur, rowptr, col);

    const int AB = NN / 8;  // 12500 (exact)

    // layer 0 aggregate
    aggregate_kernel<<<AB, 256, 0, stream>>>(hf8, As, Ad, rowptr, col, b0, abf, 1);
    // layer 1
    gemm_mfma_kernel<128><<<GB, 256, 0, stream>>>(abf, W1, as1, ad1, hf8, As, Ad);
    aggregate_kernel<<<AB, 256, 0, stream>>>(hf8, As, Ad, rowptr, col, b1, abf, 1);
    // layer 2 (plain aggregate with bias b2; readout unfused)
    gemm_mfma_kernel<128><<<GB, 256, 0, stream>>>(abf, W2, as2, ad2, hf8, As, Ad);
    aggregate_kernel<<<AB, 256, 0, stream>>>(hf8, As, Ad, rowptr, col, b2, abf, 0);

    // readout
    sum_kernel<<<256, 256, 0, stream>>>(abf, g);
    finalize_kernel<<<1, 128, 0, stream>>>(g, Wp, bp, out);
}